// Round 14
// baseline (1331.149 us; speedup 1.0000x reference)
//
#include <hip/hip_runtime.h>

// WaveNet (nsynth batch-folding) on MI355X — persistent kernel, v14.
// Stream identity: batch-folding dilation == dilated conv over one 8192-sample
// stream, j = l*2 + n; fold-d taps at j +- 2d, zero-pad at stream ends.
//
// v14 = v13 + channel-split block PAIRS: blocks b and b+128 (same XCD) share
// one 64-sample tile. Member m computes gate/feat channels [128m,128m+128)
// (phase 1) and thru->H (m=0) / skip->S (m=1) (phase 2). Each block reads
// 512KB weights/layer (was 1MB) -> per-XCD L2 weight traffic halves; 256
// blocks keep full parallelism. res halves exchanged via a same-XCD pair
// flag + pre-swizzled global mirror DMA'd into LDS (issued before the ring
// refill so vmcnt(6) retires it in-order). Weights stay in v13's DMA-burst
// WF layout (re-derived for pair geometry). H/S fp32 masters in registers;
// S never touches memory until the final GEMM.

#define TS 8192
#define NL 30
#define NBLK 256
#define WF_LAYER 524288   // hw per layer = 32 chunks x 2 members x 8 waves x 1024

typedef __attribute__((ext_vector_type(8))) short bf16x8;
typedef __attribute__((ext_vector_type(4))) float f32x4;

__device__ __forceinline__ unsigned short f2bf(float f) {
    union { float f; unsigned int u; } v; v.f = f;
    unsigned int u = v.u;
    u += 0x7fffu + ((u >> 16) & 1u);   // RNE
    return (unsigned short)(u >> 16);
}

__device__ __forceinline__ void gload_lds16(const void* g, void* l) {
    __builtin_amdgcn_global_load_lds(
        (const __attribute__((address_space(1))) void*)g,
        (__attribute__((address_space(3))) void*)l, 16, 0, 0);
}

#define VMW6()  asm volatile("s_waitcnt vmcnt(6)" ::: "memory")
#define VMW4()  asm volatile("s_waitcnt vmcnt(4)" ::: "memory")
#define VMW2()  asm volatile("s_waitcnt vmcnt(2)" ::: "memory")
#define VMW0()  asm volatile("s_waitcnt vmcnt(0)" ::: "memory")
#define LGKM0() asm volatile("s_waitcnt lgkmcnt(0)" ::: "memory")
#define SBAR()  __builtin_amdgcn_s_barrier()
#define MFMA16(a, b, c) __builtin_amdgcn_mfma_f32_16x16x32_bf16((a), (b), (c), 0, 0, 0)

// ---------------------------------------------------------------------------
// Weight prep -> WF fragment-burst layout (pair geometry).
// hw offset: ((((k*32 + c)*2 + mm)*8 + w)*2 + inst)*512 + lane*8 + e
// rsub = lane>>2, slot = (lane&3)^((lane>>3)&3), K col = kc*32 + slot*8 + e
// c<24 : t=c>>3, kc=c&7; row o = mm*128 + 16w + rsub;
//        inst0 -> gate gw[k][o][col][t], inst1 -> feat fw[k][o][col][t]
// c>=24: kc=c-24; row o2 = 32w + inst*16 + rsub;
//        mm0 -> thru tw[k][o2][col], mm1 -> skip sw[k][o2][col]
// ---------------------------------------------------------------------------
__global__ void prep_weights_kernel(
    const float* __restrict__ gw, const float* __restrict__ fw,
    const float* __restrict__ tw, const float* __restrict__ sw,
    const float* __restrict__ iw, const float* __restrict__ fnw,
    unsigned short* __restrict__ WF,
    unsigned short* __restrict__ Wib, unsigned short* __restrict__ Wfb)
{
    const int idx = blockIdx.x * blockDim.x + threadIdx.x;
    const int stride = gridDim.x * blockDim.x;
    const int total = NL << 16;               // (k,c,mm,w,inst,lane) groups of 8
    for (int i = idx; i < total; i += stride) {
        const int lane = i & 63;
        const int inst = (i >> 6) & 1;
        const int w    = (i >> 7) & 7;
        const int mm   = (i >> 10) & 1;
        const int c    = (i >> 11) & 31;
        const int k    = i >> 16;
        const int rsub = lane >> 2;
        const int slot = (lane & 3) ^ ((lane >> 3) & 3);
        unsigned short* dst = WF + (size_t)i * 8;
        if (c < 24) {
            const int t = c >> 3, kc = c & 7;
            const int o   = mm * 128 + 16 * w + rsub;
            const int col = kc * 32 + slot * 8;
            const float* src = ((inst == 0) ? gw : fw)
                               + ((size_t)(k * 256 + o) * 256 + col) * 3 + t;
            #pragma unroll
            for (int e = 0; e < 8; ++e) dst[e] = f2bf(src[e * 3]);
        } else {
            const int kc = c - 24;
            const int o2  = 32 * w + inst * 16 + rsub;
            const int col = kc * 32 + slot * 8;
            const float* src = ((mm == 0) ? tw : sw)
                               + (size_t)(k * 256 + o2) * 256 + col;
            #pragma unroll
            for (int e = 0; e < 8; ++e) dst[e] = f2bf(src[e]);
        }
    }
    for (int i = idx; i < 256 * 256; i += stride) Wib[i] = f2bf(iw[i]);
    for (int i = idx; i < 256 * 256; i += stride) Wfb[i] = f2bf(fnw[i]);
}

// ---------------------------------------------------------------------------
__device__ __forceinline__ void grid_barrier(unsigned* cnt, unsigned target, int tid) {
    __syncthreads();
    if (tid == 0) {
        __hip_atomic_fetch_add(cnt, 1u, __ATOMIC_RELEASE, __HIP_MEMORY_SCOPE_AGENT);
        while (__hip_atomic_load(cnt, __ATOMIC_RELAXED, __HIP_MEMORY_SCOPE_AGENT) < target)
            __builtin_amdgcn_s_sleep(2);
        (void)__hip_atomic_load(cnt, __ATOMIC_ACQUIRE, __HIP_MEMORY_SCOPE_AGENT);
    }
    __syncthreads();
}

// ---------------------------------------------------------------------------
// B-chunk staging from WF: chunk c in [0,32), 2KB per (chunk, member, wave),
// two contiguous 1KB bursts. Ring-4 per wave (buf = c&3).
// ---------------------------------------------------------------------------
__device__ __forceinline__ void stage32(
    const unsigned short* __restrict__ WFk,
    unsigned short* B_lds, int c, int m, int w, int lane)
{
    unsigned short* dst = B_lds + w * 4096 + (c & 3) * 1024;
    const unsigned short* src = WFk + ((size_t)((c * 2 + m) * 8 + w) << 10) + lane * 8;
    gload_lds16(src, dst);
    gload_lds16(src + 512, dst + 512);
}

// read B fragment: local row r (0..31), k-quarter krow (0..3)
__device__ __forceinline__ bf16x8 bread(const unsigned short* Bw, int r, int krow)
{
    return *(const bf16x8*)(Bw + r * 32 + ((krow ^ ((r >> 1) & 3)) << 3));
}

// ---------------------------------------------------------------------------
__global__ __launch_bounds__(512, 2)
void wavenet_kernel(const float* __restrict__ x,
                    const float* __restrict__ init_w,
                    const float* __restrict__ init_b,
                    const unsigned short* __restrict__ Wib,
                    const float* __restrict__ ib,
                    const unsigned short* __restrict__ WF,
                    const float* __restrict__ gbA,
                    const float* __restrict__ fbA,
                    const unsigned short* __restrict__ Wfb,
                    const float* __restrict__ fbias,
                    unsigned short* __restrict__ Hb0,
                    unsigned short* __restrict__ Hb1,
                    unsigned short* __restrict__ resbuf,
                    unsigned* __restrict__ flags,
                    float* __restrict__ out,
                    unsigned* __restrict__ counter)
{
    __shared__ __align__(16) unsigned short A_lds[3 * 64 * 256];   // 96 KB (tap0 doubles as res/S)
    __shared__ __align__(16) unsigned short B_lds[8 * 4 * 1024];   // 64 KB

    const int tid  = threadIdx.x;
    const int lane = tid & 63;
    const int w    = tid >> 6;
    const int bid  = blockIdx.x;
    const int p    = bid & 127;        // pair id (both members same XCD: p%8)
    const int m    = bid >> 7;         // member 0/1
    const int om   = 1 - m;
    const int j0   = ((((p & 7) << 4) | (p >> 3))) * 64;
    const int arow = lane & 15;
    const int krow = lane >> 4;
    const int aswz = (arow & 7) << 4;

    // persistent fp32 master: wave w owns cols [32w,32w+32) of H (m=0) / S (m=1)
    f32x4 state[4][2];

    // ================= init conv: both members compute H0 -> LDS tap1 ======
    #pragma unroll
    for (int mt = 0; mt < 4; ++mt)
        #pragma unroll
        for (int ct = 0; ct < 2; ++ct) {
            const int col = 32 * w + ct * 16 + arow;
            const float w0 = init_w[col * 3];
            const float w1 = init_w[col * 3 + 1];
            const float w2 = init_w[col * 3 + 2];
            const float b  = init_b[col];
            #pragma unroll
            for (int i = 0; i < 4; ++i) {
                const int row = mt * 16 + krow * 4 + i;
                const int j = j0 + row;
                float acc = b + w1 * x[(j & 1) * 4096 + (j >> 1)];
                int i2 = j - 2;
                if (i2 >= 0) acc += w0 * x[(i2 & 1) * 4096 + (i2 >> 1)];
                i2 = j + 2;
                if (i2 < TS) acc += w2 * x[(i2 & 1) * 4096 + (i2 >> 1)];
                const unsigned short hb = f2bf(acc);
                if (m == 0) {
                    state[mt][ct][i] = acc;
                    Hb0[(j << 8) + col] = hb;
                }
                A_lds[((64 + row) << 8) + (((col << 1) ^ ((row & 7) << 4)) >> 1)] = hb;
            }
        }
    LGKM0(); SBAR();   // H0 visible in tap1

    // ================= iskip (member 1): S = ib + H0 @ Wib^T ===============
    if (m == 1) {
        const int cs = 32 * w;
        #pragma unroll
        for (int ct = 0; ct < 2; ++ct) {
            const float b = ib[cs + ct * 16 + arow];
            #pragma unroll
            for (int mt = 0; mt < 4; ++mt)
                state[mt][ct] = (f32x4){b, b, b, b};
        }
        #pragma unroll
        for (int kc = 0; kc < 8; ++kc) {
            const int aoff = ((kc * 64 + krow * 16) ^ aswz) >> 1;
            bf16x8 a[4];
            #pragma unroll
            for (int mt = 0; mt < 4; ++mt)
                a[mt] = *(const bf16x8*)(A_lds + ((64 + mt * 16 + arow) << 8) + aoff);
            const int koff = kc * 32 + krow * 8;
            const bf16x8 b0 = *(const bf16x8*)(Wib + ((cs + arow) << 8) + koff);
            const bf16x8 b1 = *(const bf16x8*)(Wib + ((cs + 16 + arow) << 8) + koff);
            #pragma unroll
            for (int mt = 0; mt < 4; ++mt) {
                state[mt][0] = MFMA16(a[mt], b0, state[mt][0]);
                state[mt][1] = MFMA16(a[mt], b1, state[mt][1]);
            }
        }
    }

    // prefetch layer-0 chunks 0..2 (drained by the grid barrier)
    stage32(WF, B_lds, 0, m, w, lane);
    stage32(WF, B_lds, 1, m, w, lane);
    stage32(WF, B_lds, 2, m, w, lane);

    unsigned target = NBLK;
    grid_barrier(counter, target, tid);

    const unsigned short* Hb_in = Hb0;
    unsigned short*       Hb_out = Hb1;

    // ============================ layer loop ================================
    for (int k = 0; k < NL; ++k) {
        const int d = 2 << (k % 10);   // stream dilation
        const unsigned short* WFk = WF + (size_t)k * WF_LAYER;

        // ---- A-stage: all 3 taps from global Hb ----
        #pragma unroll
        for (int q = 0; q < 12; ++q) {
            const int cc   = tid + q * 512;     // 0..6143
            const int c16  = cc & 31;
            const int mrow = (cc >> 5) & 63;
            const int tap  = cc >> 11;          // 0..2
            const int r    = j0 + mrow + (tap - 1) * d;
            uint4 v = make_uint4(0u, 0u, 0u, 0u);
            if (r >= 0 && r < TS)
                v = *(const uint4*)(Hb_in + (r << 8) + (c16 << 3));
            const int sb = ((c16 << 4) ^ ((mrow & 7) << 4)) >> 1;
            *(uint4*)(A_lds + ((tap * 64 + mrow) << 8) + sb) = v;
        }
        LGKM0(); SBAR();   // A complete (chunks 0..2 already landed)

        // ---- phase 1: 24 chunk-steps (t x kc; gate+feat per chunk) ----
        const float gv = gbA[k * 256 + m * 128 + 16 * w + arow];
        const float fv = fbA[k * 256 + m * 128 + 16 * w + arow];
        f32x4 accG[4], accF[4];
        #pragma unroll
        for (int mt = 0; mt < 4; ++mt) {
            accG[mt] = (f32x4){gv, gv, gv, gv};
            accF[mt] = (f32x4){fv, fv, fv, fv};
        }

        #pragma unroll
        for (int s = 0; s < 24; ++s) {
            if (s < 21)      { stage32(WFk, B_lds, s + 3, m, w, lane); VMW6(); }
            else if (s == 21){ VMW4(); }
            else if (s == 22){ VMW2(); }
            else             { VMW0(); }
            const int t = s >> 3, kc = s & 7;
            const int aoff = ((kc * 64 + krow * 16) ^ aswz) >> 1;
            bf16x8 a[4];
            #pragma unroll
            for (int mt = 0; mt < 4; ++mt)
                a[mt] = *(const bf16x8*)(A_lds + ((t * 64 + mt * 16 + arow) << 8) + aoff);
            const unsigned short* Bw = B_lds + w * 4096 + (s & 3) * 1024;
            const bf16x8 bg  = bread(Bw, arow, krow);
            const bf16x8 bf_ = bread(Bw, 16 + arow, krow);
            #pragma unroll
            for (int mt = 0; mt < 4; ++mt) {
                accG[mt] = MFMA16(a[mt], bg,  accG[mt]);
                accF[mt] = MFMA16(a[mt], bf_, accF[mt]);
            }
        }

        LGKM0(); SBAR();   // all tap reads done (tap0 reused for res)

        // ---- res = sigmoid(G)*tanh(F): own half -> LDS [m] + global mirror ----
        #pragma unroll
        for (int mt = 0; mt < 4; ++mt)
            #pragma unroll
            for (int i = 0; i < 4; ++i) {
                const float g = accG[mt][i];
                const float f = accF[mt][i];
                const float sg = 1.0f / (1.0f + __expf(-g));
                const float e2 = __expf(2.0f * f);
                const float th = 1.0f - 2.0f / (e2 + 1.0f);
                const unsigned short hb = f2bf(sg * th);
                const int row  = mt * 16 + krow * 4 + i;
                const int colp = 16 * w + arow;                   // within half
                const int hwo  = ((colp << 1) ^ ((row & 7) << 4)) >> 1;
                A_lds[m * 8192 + row * 128 + hwo] = hb;
                resbuf[(size_t)((p * 2 + m) * 64 + row) * 128 + hwo] = hb;
            }
        __syncthreads();   // res stores drained + own half visible

        // ---- pair exchange: flag release + spin (same-XCD L2) ----
        if (tid == 0) {
            __hip_atomic_store(&flags[p * 2 + m], (unsigned)(k + 1),
                               __ATOMIC_RELEASE, __HIP_MEMORY_SCOPE_AGENT);
            while (__hip_atomic_load(&flags[p * 2 + om], __ATOMIC_ACQUIRE,
                                     __HIP_MEMORY_SCOPE_AGENT) < (unsigned)(k + 1))
                __builtin_amdgcn_s_sleep(1);
        }
        __syncthreads();

        if (k == NL - 1 && m == 0) return;   // m=0's last phase 2 is dead

        // partner half DMA first (so VMW6 retires it), then ring refill 24..26
        {
            const unsigned short* src = resbuf
                + (size_t)((p * 2 + om) * 64 + 8 * w) * 128 + lane * 8;
            unsigned short* dst = A_lds + om * 8192 + w * 1024;
            gload_lds16(src, dst);
            gload_lds16(src + 512, dst + 512);
        }
        stage32(WFk, B_lds, 24, m, w, lane);
        stage32(WFk, B_lds, 25, m, w, lane);
        stage32(WFk, B_lds, 26, m, w, lane);
        VMW6();            // partner res landed (oldest 2 of 8)
        SBAR();            // all waves' partner slices in LDS

        // ---- phase 2: 8 chunk-steps over K=256 res; acc from state ----
        f32x4 acc2[4][2];
        #pragma unroll
        for (int mt = 0; mt < 4; ++mt)
            #pragma unroll
            for (int ct = 0; ct < 2; ++ct)
                acc2[mt][ct] = state[mt][ct];

        #pragma unroll
        for (int p2 = 0; p2 < 8; ++p2) {
            if (p2 < 5)      { stage32(WFk, B_lds, 27 + p2, m, w, lane); VMW6(); }
            else if (p2 == 5){ VMW4(); }
            else if (p2 == 6){ VMW2(); }
            else             { VMW0(); }
            const int kc = p2;
            const int mm = kc >> 2, kc4 = kc & 3;
            const int aoff = ((kc4 * 64 + krow * 16) ^ aswz) >> 1;
            bf16x8 a[4];
            #pragma unroll
            for (int mt = 0; mt < 4; ++mt)
                a[mt] = *(const bf16x8*)(A_lds + mm * 8192 + (mt * 16 + arow) * 128 + aoff);
            const unsigned short* Bw = B_lds + w * 4096 + ((24 + p2) & 3) * 1024;
            const bf16x8 b0 = bread(Bw, arow, krow);
            const bf16x8 b1 = bread(Bw, 16 + arow, krow);
            #pragma unroll
            for (int mt = 0; mt < 4; ++mt) {
                acc2[mt][0] = MFMA16(a[mt], b0, acc2[mt][0]);
                acc2[mt][1] = MFMA16(a[mt], b1, acc2[mt][1]);
            }
        }

        #pragma unroll
        for (int mt = 0; mt < 4; ++mt)
            #pragma unroll
            for (int ct = 0; ct < 2; ++ct)
                state[mt][ct] = acc2[mt][ct];

        if (k < NL - 1) {
            // next-layer ring prefetch (bufs 0..2 free after p2=7 consumed buf 3)
            stage32(WFk + WF_LAYER, B_lds, 0, m, w, lane);
            stage32(WFk + WF_LAYER, B_lds, 1, m, w, lane);
            stage32(WFk + WF_LAYER, B_lds, 2, m, w, lane);

            if (m == 0) {   // publish bf16 H
                #pragma unroll
                for (int mt = 0; mt < 4; ++mt)
                    #pragma unroll
                    for (int ct = 0; ct < 2; ++ct)
                        #pragma unroll
                        for (int i = 0; i < 4; ++i) {
                            const int row = mt * 16 + krow * 4 + i;
                            const int col = 32 * w + ct * 16 + arow;
                            Hb_out[((j0 + row) << 8) + col] = f2bf(state[mt][ct][i]);
                        }
            }
            target += NBLK;
            grid_barrier(counter, target, tid);   // drains prefetch + publishes H

            unsigned short* tmp = (unsigned short*)Hb_in;
            Hb_in = Hb_out; Hb_out = tmp;
        } else {
            // last layer, member 1: S -> tap0 ([mm][row][col']) for final GEMM
            LGKM0(); SBAR();
            #pragma unroll
            for (int mt = 0; mt < 4; ++mt)
                #pragma unroll
                for (int ct = 0; ct < 2; ++ct)
                    #pragma unroll
                    for (int i = 0; i < 4; ++i) {
                        const int row = mt * 16 + krow * 4 + i;
                        const int col = 32 * w + ct * 16 + arow;
                        const int mm = col >> 7, colp = col & 127;
                        A_lds[mm * 8192 + row * 128 +
                              (((colp << 1) ^ ((row & 7) << 4)) >> 1)] =
                            f2bf(state[mt][ct][i]);
                    }
            LGKM0(); SBAR();
        }
    }

    // ================= final (member 1): out = Wfb @ S^T + fbias ============
    {
        const int m0 = w * 32;
        f32x4 facc[2][4];
        #pragma unroll
        for (int cf = 0; cf < 2; ++cf)
            #pragma unroll
            for (int jf = 0; jf < 4; ++jf)
                facc[cf][jf] = (f32x4){0.f, 0.f, 0.f, 0.f};

        #pragma unroll
        for (int kc = 0; kc < 8; ++kc) {
            const int koff = kc * 32 + krow * 8;
            const bf16x8 a0 = *(const bf16x8*)(Wfb + ((m0 + arow) << 8) + koff);
            const bf16x8 a1 = *(const bf16x8*)(Wfb + ((m0 + 16 + arow) << 8) + koff);
            const int mm = kc >> 2, kc4 = kc & 3;
            const int aoff = ((kc4 * 64 + krow * 16) ^ aswz) >> 1;
            #pragma unroll
            for (int jf = 0; jf < 4; ++jf) {
                const bf16x8 b = *(const bf16x8*)(A_lds + mm * 8192 +
                                                  (jf * 16 + arow) * 128 + aoff);
                facc[0][jf] = MFMA16(a0, b, facc[0][jf]);
                facc[1][jf] = MFMA16(a1, b, facc[1][jf]);
            }
        }

        #pragma unroll
        for (int cf = 0; cf < 2; ++cf)
            #pragma unroll
            for (int jf = 0; jf < 4; ++jf)
                #pragma unroll
                for (int i = 0; i < 4; ++i) {
                    const int co = m0 + cf * 16 + krow * 4 + i;
                    const int jj = j0 + jf * 16 + arow;
                    out[((jj & 1) << 20) + (co << 12) + (jj >> 1)] = facc[cf][jf][i] + fbias[co];
                }
    }
}

// ---------------------------------------------------------------------------
extern "C" void kernel_launch(void* const* d_in, const int* in_sizes, int n_in,
                              void* d_out, int out_size, void* d_ws, size_t ws_size,
                              hipStream_t stream)
{
    const float* x       = (const float*)d_in[0];
    const float* init_w  = (const float*)d_in[1];
    const float* init_b  = (const float*)d_in[2];
    const float* iskip_w = (const float*)d_in[3];
    const float* iskip_b = (const float*)d_in[4];
    const float* gate_w  = (const float*)d_in[5];
    const float* gate_b  = (const float*)d_in[6];
    const float* feat_w  = (const float*)d_in[7];
    const float* feat_b  = (const float*)d_in[8];
    const float* skip_w  = (const float*)d_in[9];
    const float* thru_w  = (const float*)d_in[10];
    const float* final_w = (const float*)d_in[11];
    const float* final_b = (const float*)d_in[12];

    char* ws = (char*)d_ws;
    size_t off = 0;
    auto alloc = [&](size_t bytes) {
        void* p = ws + off;
        off += (bytes + 255) & ~(size_t)255;
        return p;
    };
    unsigned short* WF   = (unsigned short*)alloc((size_t)NL * WF_LAYER * 2);
    unsigned short* Wib  = (unsigned short*)alloc(256 * 256 * 2);
    unsigned short* Wfb  = (unsigned short*)alloc(256 * 256 * 2);
    unsigned short* Hb0  = (unsigned short*)alloc((size_t)TS * 256 * 2);
    unsigned short* Hb1  = (unsigned short*)alloc((size_t)TS * 256 * 2);
    unsigned short* resb = (unsigned short*)alloc((size_t)128 * 2 * 64 * 128 * 2);
    unsigned*       cnt  = (unsigned*)alloc(256);
    unsigned*       flg  = (unsigned*)alloc(1024);

    hipMemsetAsync((void*)cnt, 0, 256 + 1024, stream);
    prep_weights_kernel<<<2048, 256, 0, stream>>>(gate_w, feat_w, thru_w, skip_w,
                                                  iskip_w, final_w, WF, Wib, Wfb);
    wavenet_kernel<<<NBLK, 512, 0, stream>>>(
        x, init_w, init_b, Wib, iskip_b, WF, gate_b, feat_b,
        Wfb, final_b, Hb0, Hb1, resb, flg, (float*)d_out, cnt);
}